// Round 1
// 284.251 us; speedup vs baseline: 1.1521x; 1.1521x over previous
//
#include <hip/hip_runtime.h>

#define TT   256
#define HID  30
#define LOG2E 1.4426950408889634f
#define HS   40   // h-row stride in bf16: 80B -> b128 rows stay 16B-aligned, ~2-way banks

typedef __bf16 bf16x8_t __attribute__((ext_vector_type(8)));
typedef float  f32x4_t  __attribute__((ext_vector_type(4)));

__device__ __forceinline__ float fexp2(float x){
#if __has_builtin(__builtin_amdgcn_exp2f)
    return __builtin_amdgcn_exp2f(x);
#else
    return exp2f(x);
#endif
}
__device__ __forceinline__ float frcp(float x){
#if __has_builtin(__builtin_amdgcn_rcpf)
    return __builtin_amdgcn_rcpf(x);
#else
    return 1.f/x;
#endif
}
__device__ __forceinline__ float fsigmoid(float x){ return frcp(1.f + fexp2(-LOG2E*x)); }
__device__ __forceinline__ f32x4_t exp4(f32x4_t v){
    f32x4_t e; e[0]=fexp2(v[0]); e[1]=fexp2(v[1]); e[2]=fexp2(v[2]); e[3]=fexp2(v[3]); return e;
}
__device__ __forceinline__ f32x4_t rcp4(f32x4_t v){
    f32x4_t r; r[0]=frcp(v[0]); r[1]=frcp(v[1]); r[2]=frcp(v[2]); r[3]=frcp(v[3]); return r;
}
__device__ __forceinline__ f32x4_t splat4(float v){ f32x4_t r = {v,v,v,v}; return r; }

// Gate-per-MFMA layout: accs arrive pre-scaled into exp2 domain
//   aI,aF,aO = -LOG2E*z ; aG = +2*LOG2E*z
// Fused activations (all lane-local, zero cross-lane):
//   i*tanh(zg) = (eG-1) / ((1+eI)*(eG+1))     [one rcp for the product]
//   f          = 1/(1+eF)
//   o*tanh(c)  = (eC-1) / ((1+eO)*(eC+1)),  eC = e^{2c}
__device__ __forceinline__ f32x4_t lstm_act(f32x4_t aI, f32x4_t aF, f32x4_t aG,
                                            f32x4_t aO, f32x4_t& cst){
    f32x4_t eI = exp4(aI);
    f32x4_t eF = exp4(aF);
    f32x4_t eG = exp4(aG);
    f32x4_t eO = exp4(aO);
    f32x4_t f  = rcp4(eF + 1.f);
    f32x4_t tG = eG + 1.f;
    f32x4_t p  = (eG - 1.f) * rcp4(eI*tG + tG);   // i * tanh(zg)
    cst = f*cst + p;
    f32x4_t cc;                                    // clamp so e^{2c} can't overflow
    cc[0]=fminf(fmaxf(cst[0],-30.f),30.f);
    cc[1]=fminf(fmaxf(cst[1],-30.f),30.f);
    cc[2]=fminf(fmaxf(cst[2],-30.f),30.f);
    cc[3]=fminf(fmaxf(cst[3],-30.f),30.f);
    f32x4_t eC = exp4(cc * (2.f*LOG2E));
    f32x4_t tC = eC + 1.f;
    return (eC - 1.f) * rcp4(eO*tC + tC);          // h = o * tanh(c)
}

// 256-thread blocks, 4 waves: wv0,1 = layer0 (unit halves 0-15 / 16-29),
// wv2,3 = layer1. Skewed pipeline as before (layer1 trails layer0 by 1 step),
// double-buffered bf16 h tiles in LDS, 1 barrier per step.
__global__ __launch_bounds__(256, 2)
void lstm_fused(const float* __restrict__ x,
    const float* __restrict__ Wih0, const float* __restrict__ Whh0,
    const float* __restrict__ bih0, const float* __restrict__ bhh0,
    const float* __restrict__ Wih1, const float* __restrict__ Whh1,
    const float* __restrict__ bih1, const float* __restrict__ bhh1,
    const float* __restrict__ Wfc1, const float* __restrict__ bfc1,
    const float* __restrict__ Wfc2, const float* __restrict__ bfc2,
    const float* __restrict__ Wfc3, const float* __restrict__ bfc3,
    float* __restrict__ out)
{
    __shared__ __align__(16) __bf16 h0f[2][16][HS];  // k=30,31: x0,x1 slots
    __shared__ __align__(16) __bf16 h1f[2][16][HS];  // k>=30 stays 0
    __shared__ float h1_last[16*32];
    __shared__ float zbuf[16*64];
    __shared__ float z2buf[16*32];

    const int tid  = threadIdx.x;
    const int lane = tid & 63;
    const int wv   = tid >> 6;         // 0..3
    const int lay  = wv >> 1;          // 0: layer0, 1: layer1
    const int uh   = wv & 1;           // unit half
    const int n    = lane & 15;
    const int q    = lane >> 4;
    const int q4   = q*4;
    const int u    = uh*16 + n;        // hidden unit (col)
    const bool colok = (u < HID);
    const int uq   = colok ? u : 0;
    const int bbase = blockIdx.x * 16;

    // ---- resident per-gate B-fragments, scale folded into bf16 weights ----
    bf16x8_t fA[4], fB[4];             // fA: Whh0+Wih0 | Wih1 ; fB: Whh1 (layer1 only)
    float bv[4], wx[4];
    {
        const float scl[4] = {-LOG2E, -LOG2E, 2.f*LOG2E, -LOG2E}; // i,f,g,o
        #pragma unroll
        for (int g = 0; g < 4; ++g) {
            const int row = g*HID + uq;
            const float sg = scl[g];
            bf16x8_t va{}, vb{};
            #pragma unroll
            for (int j = 0; j < 8; ++j) {
                int k = q*8 + j;
                float wa = 0.f, wb = 0.f;
                if (colok) {
                    if (lay == 0) {
                        if (k < HID)      wa = Whh0[row*HID + k];
                        else if (k < 32)  wa = Wih0[row*3 + (k - HID)];
                    } else {
                        if (k < HID) { wa = Wih1[row*HID + k];  wb = Whh1[row*HID + k]; }
                    }
                }
                va[j] = (__bf16)(sg*wa);
                vb[j] = (__bf16)(sg*wb);
            }
            fA[g] = va;  fB[g] = vb;
            float bb = 0.f, ww = 0.f;
            if (colok) {
                bb = lay ? (bih1[row] + bhh1[row]) : (bih0[row] + bhh0[row]);
                if (lay == 0) ww = Wih0[row*3 + 2];
            }
            bv[g] = sg*bb;  wx[g] = sg*ww;
        }
    }

    f32x4_t cst = {0.f,0.f,0.f,0.f};

    for (int i = tid; i < 2*16*HS; i += 256) {
        (&h0f[0][0][0])[i] = (__bf16)0.f;
        (&h1f[0][0][0])[i] = (__bf16)0.f;
    }
    __syncthreads();
    if (tid < 32) {    // x0,x1(t=0) into prologue read-buffer h0f[1]
        int m = tid >> 1, cc = tid & 1;
        h0f[1][m][30+cc] = (__bf16)x[(size_t)(bbase+m)*(TT*3) + cc];
    }
    __syncthreads();

    // x addressing: SGPR base + fixed VGPR offsets
    const float* xB = x + (size_t)bbase*(TT*3);
    const int xo2  = (q*4)*(TT*3) + 2;             // + r*TT*3 for r=0..3
    const int xo01 = (tid>>1)*(TT*3) + (tid&1);
    f32x4_t x2 = {0.f,0.f,0.f,0.f};
    if (lay == 0) {   // x2(t=0)
        x2[0]=xB[xo2]; x2[1]=xB[xo2+TT*3]; x2[2]=xB[xo2+2*TT*3]; x2[3]=xB[xo2+3*TT*3];
    }

#define STEP(S, RB, WB, FIRST) do {                                            \
    if (lay == 0) {                                                            \
        bf16x8_t A0 = *(const bf16x8_t*)(&h0f[RB][n][q*8]);                    \
        f32x4_t aI = __builtin_amdgcn_mfma_f32_16x16x32_bf16(A0, fA[0], x2*wx[0] + bv[0], 0,0,0); \
        f32x4_t aF = __builtin_amdgcn_mfma_f32_16x16x32_bf16(A0, fA[1], x2*wx[1] + bv[1], 0,0,0); \
        f32x4_t aG = __builtin_amdgcn_mfma_f32_16x16x32_bf16(A0, fA[2], x2*wx[2] + bv[2], 0,0,0); \
        f32x4_t aO = __builtin_amdgcn_mfma_f32_16x16x32_bf16(A0, fA[3], x2*wx[3] + bv[3], 0,0,0); \
        const int tpre = ((S)+2 < TT) ? (S)+2 : TT-1;                          \
        const float* xs = xB + 3*tpre;                                         \
        f32x4_t x2n;                                                           \
        x2n[0]=xs[xo2]; x2n[1]=xs[xo2+TT*3];                                   \
        x2n[2]=xs[xo2+2*TT*3]; x2n[3]=xs[xo2+3*TT*3];                          \
        float x01v = 0.f;                                                      \
        if (tid < 32) x01v = xs[xo01];                                         \
        f32x4_t h = lstm_act(aI, aF, aG, aO, cst);                             \
        if (colok) {                                                           \
            h0f[WB][q4  ][u] = (__bf16)h[0];                                   \
            h0f[WB][q4+1][u] = (__bf16)h[1];                                   \
            h0f[WB][q4+2][u] = (__bf16)h[2];                                   \
            h0f[WB][q4+3][u] = (__bf16)h[3];                                   \
        }                                                                      \
        if (tid < 32) h0f[WB][tid>>1][30+(tid&1)] = (__bf16)x01v;              \
        x2 = x2n;                                                              \
    } else if (!(FIRST)) {                                                     \
        bf16x8_t A1 = *(const bf16x8_t*)(&h0f[RB][n][q*8]);                    \
        bf16x8_t A2 = *(const bf16x8_t*)(&h1f[RB][n][q*8]);                    \
        f32x4_t aI = __builtin_amdgcn_mfma_f32_16x16x32_bf16(A2, fB[0], splat4(bv[0]), 0,0,0); \
        aI         = __builtin_amdgcn_mfma_f32_16x16x32_bf16(A1, fA[0], aI, 0,0,0); \
        f32x4_t aF = __builtin_amdgcn_mfma_f32_16x16x32_bf16(A2, fB[1], splat4(bv[1]), 0,0,0); \
        aF         = __builtin_amdgcn_mfma_f32_16x16x32_bf16(A1, fA[1], aF, 0,0,0); \
        f32x4_t aG = __builtin_amdgcn_mfma_f32_16x16x32_bf16(A2, fB[2], splat4(bv[2]), 0,0,0); \
        aG         = __builtin_amdgcn_mfma_f32_16x16x32_bf16(A1, fA[2], aG, 0,0,0); \
        f32x4_t aO = __builtin_amdgcn_mfma_f32_16x16x32_bf16(A2, fB[3], splat4(bv[3]), 0,0,0); \
        aO         = __builtin_amdgcn_mfma_f32_16x16x32_bf16(A1, fA[3], aO, 0,0,0); \
        f32x4_t h = lstm_act(aI, aF, aG, aO, cst);                             \
        if (colok) {                                                           \
            h1f[WB][q4  ][u] = (__bf16)h[0];                                   \
            h1f[WB][q4+1][u] = (__bf16)h[1];                                   \
            h1f[WB][q4+2][u] = (__bf16)h[2];                                   \
            h1f[WB][q4+3][u] = (__bf16)h[3];                                   \
            if ((S) == TT-1) {                                                 \
                h1_last[(q4  )*32+u] = h[0];                                   \
                h1_last[(q4+1)*32+u] = h[1];                                   \
                h1_last[(q4+2)*32+u] = h[2];                                   \
                h1_last[(q4+3)*32+u] = h[3];                                   \
            }                                                                  \
        }                                                                      \
    }                                                                          \
    __syncthreads();                                                           \
} while (0)

    STEP(-1, 1, 0, 1);          // prologue: layer0 t=0 only
    #pragma unroll 1
    for (int s = 0; s < TT; s += 2) {
        STEP(s,   0, 1, 0);
        STEP(s+1, 1, 0, 0);
    }
#undef STEP

    // ---- FC head (256 threads) ----
    #pragma unroll
    for (int rep = 0; rep < 4; ++rep) {
        int idx = tid + rep*256;          // 16*64 outputs
        int m = idx >> 6, uu = idx & 63;
        float a = bfc1[uu];
        for (int k = 0; k < HID; ++k) a += h1_last[m*32+k] * Wfc1[uu*HID+k];
        zbuf[m*64+uu] = fmaxf(a, 0.f);
    }
    __syncthreads();
    #pragma unroll
    for (int rep = 0; rep < 2; ++rep) {
        int idx = tid + rep*256;          // 16*32 outputs
        int m = idx >> 5, v = idx & 31;
        float a = bfc2[v];
        for (int k = 0; k < 64; ++k) a += zbuf[m*64+k] * Wfc2[v*64+k];
        z2buf[m*32+v] = fmaxf(a, 0.f);
    }
    __syncthreads();
    if (tid < 16) {
        float a = bfc3[0];
        for (int k = 0; k < 32; ++k) a += z2buf[tid*32+k] * Wfc3[k];
        out[bbase + tid] = fsigmoid(a);
    }
}

extern "C" void kernel_launch(void* const* d_in, const int* in_sizes, int n_in,
                              void* d_out, int out_size, void* d_ws, size_t ws_size,
                              hipStream_t stream) {
    const float* x    = (const float*)d_in[0];
    const float* Wih0 = (const float*)d_in[1];
    const float* Whh0 = (const float*)d_in[2];
    const float* bih0 = (const float*)d_in[3];
    const float* bhh0 = (const float*)d_in[4];
    const float* Wih1 = (const float*)d_in[5];
    const float* Whh1 = (const float*)d_in[6];
    const float* bih1 = (const float*)d_in[7];
    const float* bhh1 = (const float*)d_in[8];
    const float* Wfc1 = (const float*)d_in[9];
    const float* bfc1 = (const float*)d_in[10];
    const float* Wfc2 = (const float*)d_in[11];
    const float* bfc2 = (const float*)d_in[12];
    const float* Wfc3 = (const float*)d_in[13];
    const float* bfc3 = (const float*)d_in[14];
    float* outp = (float*)d_out;

    hipLaunchKernelGGL(lstm_fused, dim3(512), dim3(256), 0, stream,
        x, Wih0, Whh0, bih0, bhh0, Wih1, Whh1, bih1, bhh1,
        Wfc1, bfc1, Wfc2, bfc2, Wfc3, bfc3, outp);
}